// Round 11
// baseline (1060.193 us; speedup 1.0000x reference)
//
#include <hip/hip_runtime.h>

#define EMBED 768
#define HIDDEN 3072
#define SEQ 577
#define BATCH 32
#define ROWS (BATCH*SEQ)      /* 18464 */
#define KPAD 608              /* padded seq for PV K-dim (19*32) */
#define SLD 640               /* S row stride in floats */

typedef __attribute__((ext_vector_type(4))) float f32x4;
typedef __attribute__((ext_vector_type(8))) __bf16 bf16x8;
typedef unsigned int __attribute__((address_space(1))) as1_u32;
typedef unsigned int __attribute__((address_space(3))) as3_u32;

__device__ __forceinline__ unsigned short f2b(float f) {
    unsigned int u = __float_as_uint(f);
    u = u + 0x7FFFu + ((u >> 16) & 1u);   // round-to-nearest-even
    return (unsigned short)(u >> 16);
}
__device__ __forceinline__ float b2f(unsigned short s) {
    return __uint_as_float(((unsigned int)s) << 16);
}
__device__ __forceinline__ void gld16(const unsigned short* g, unsigned short* l) {
    __builtin_amdgcn_global_load_lds((const as1_u32*)g, (as3_u32*)l, 16, 0, 0);
}
// tanh-form GELU (max err vs exact-erf < 1e-3, below bf16 quantization of hid)
__device__ __forceinline__ float gelu_f(float x) {
    float u = x * (0.7978845608028654f + 0.03567740814183f * x * x);
    float e = __expf(2.0f * u);                 // +inf-safe
    float th = 1.0f - 2.0f / (e + 1.0f);
    return 0.5f * x * (1.0f + th);
}

// grid decomposition: x = col-block, y = row-block; chunked-bijective XCD swizzle (m204)
__device__ __forceinline__ int swz_lin() {
    int nx = gridDim.x;
    int lin = blockIdx.y * nx + blockIdx.x;
    if (gridDim.z == 1) {
        int nwg = nx * gridDim.y;
        int q = nwg >> 3, r = nwg & 7;
        int xcd = lin & 7, blk = lin >> 3;
        lin = (xcd < r ? xcd * (q + 1) : r * (q + 1) + (xcd - r) * q) + blk;
    }
    return lin;
}

// ---------------- LayerNorm: fp32 row -> bf16 row ----------------
__global__ void ln_kernel(const float* __restrict__ x, const float* __restrict__ g,
                          const float* __restrict__ b, unsigned short* __restrict__ o) {
    int row = blockIdx.x;
    const float* xr = x + (size_t)row * EMBED;
    int t = threadIdx.x;
    float v0 = xr[t], v1 = xr[t + 256], v2 = xr[t + 512];
    float s = v0 + v1 + v2;
    float ss = v0 * v0 + v1 * v1 + v2 * v2;
#pragma unroll
    for (int d = 32; d; d >>= 1) { s += __shfl_down(s, d); ss += __shfl_down(ss, d); }
    __shared__ float rs[4], rss[4];
    if ((t & 63) == 0) { rs[t >> 6] = s; rss[t >> 6] = ss; }
    __syncthreads();
    s = rs[0] + rs[1] + rs[2] + rs[3];
    ss = rss[0] + rss[1] + rss[2] + rss[3];
    float mu = s * (1.0f / EMBED);
    float var = ss * (1.0f / EMBED) - mu * mu;
    float rstd = rsqrtf(var + 1e-5f);
    unsigned short* orow = o + (size_t)row * EMBED;
    orow[t]       = f2b((v0 - mu) * rstd * g[t]       + b[t]);
    orow[t + 256] = f2b((v1 - mu) * rstd * g[t + 256] + b[t + 256]);
    orow[t + 512] = f2b((v2 - mu) * rstd * g[t + 512] + b[t + 512]);
}

// ---------------- LayerNorm -> hi/lo bf16 planes ----------------
__global__ void ln_split_kernel(const float* __restrict__ x, const float* __restrict__ g,
                                const float* __restrict__ b, unsigned short* __restrict__ oh,
                                unsigned short* __restrict__ ol) {
    int row = blockIdx.x;
    const float* xr = x + (size_t)row * EMBED;
    int t = threadIdx.x;
    float v0 = xr[t], v1 = xr[t + 256], v2 = xr[t + 512];
    float s = v0 + v1 + v2;
    float ss = v0 * v0 + v1 * v1 + v2 * v2;
#pragma unroll
    for (int d = 32; d; d >>= 1) { s += __shfl_down(s, d); ss += __shfl_down(ss, d); }
    __shared__ float rs[4], rss[4];
    if ((t & 63) == 0) { rs[t >> 6] = s; rss[t >> 6] = ss; }
    __syncthreads();
    s = rs[0] + rs[1] + rs[2] + rs[3];
    ss = rss[0] + rss[1] + rss[2] + rss[3];
    float mu = s * (1.0f / EMBED);
    float var = ss * (1.0f / EMBED) - mu * mu;
    float rstd = rsqrtf(var + 1e-5f);
    size_t base = (size_t)row * EMBED;
#pragma unroll
    for (int i = 0; i < 3; i++) {
        int d = t + 256 * i;
        float v = (i == 0 ? v0 : (i == 1 ? v1 : v2));
        float y = (v - mu) * rstd * g[d] + b[d];
        unsigned short h = f2b(y);
        oh[base + d] = h;
        ol[base + d] = f2b(y - b2f(h));
    }
}

// ---------------- ksq: per-row sum of K^2 from hi/lo planes (cols 768..1535) ----------------
__global__ void ksq_kernel(const unsigned short* __restrict__ qh,
                           const unsigned short* __restrict__ ql, float* __restrict__ ksq) {
    int row = blockIdx.x;
    int t = threadIdx.x;
    size_t base = (size_t)row * 1536 + EMBED;
    float s = 0.f;
#pragma unroll
    for (int i = 0; i < 3; i++) {
        int d = t + 256 * i;
        float k = b2f(qh[base + d]) + b2f(ql[base + d]);
        s += k * k;
    }
#pragma unroll
    for (int d = 32; d; d >>= 1) s += __shfl_down(s, d);
    __shared__ float rs[4];
    if ((t & 63) == 0) rs[t >> 6] = s;
    __syncthreads();
    if (t == 0) ksq[row] = rs[0] + rs[1] + rs[2] + rs[3];
}

// ---------------- row softmax of (S) -> bf16 P, zero-padded to KPAD ----------------
__global__ void softmax_kernel(const float* __restrict__ S, unsigned short* __restrict__ P) {
    int r = blockIdx.x;
    int t = threadIdx.x;
    const float* sr = S + (size_t)r * SLD;
    float v0 = sr[t];
    float v1 = sr[t + 256];
    float v2 = (t + 512 < SEQ) ? sr[t + 512] : -3.0e38f;
    float m = fmaxf(v0, fmaxf(v1, v2));
#pragma unroll
    for (int d = 32; d; d >>= 1) m = fmaxf(m, __shfl_down(m, d));
    __shared__ float rm[4];
    if ((t & 63) == 0) rm[t >> 6] = m;
    __syncthreads();
    m = fmaxf(fmaxf(rm[0], rm[1]), fmaxf(rm[2], rm[3]));
    float e0 = __expf(v0 - m);
    float e1 = __expf(v1 - m);
    float e2 = (t + 512 < SEQ) ? __expf(v2 - m) : 0.0f;
    float s = e0 + e1 + e2;
#pragma unroll
    for (int d = 32; d; d >>= 1) s += __shfl_down(s, d);
    __shared__ float rsum[4];
    if ((t & 63) == 0) rsum[t >> 6] = s;
    __syncthreads();
    float inv = 1.0f / (rsum[0] + rsum[1] + rsum[2] + rsum[3]);
    unsigned short* pr = P + (size_t)r * KPAD;
    pr[t]       = f2b(e0 * inv);
    pr[t + 256] = f2b(e1 * inv);
    if (t + 512 < KPAD) pr[t + 512] = f2b(e2 * inv);   // zeros for 577..607
}

// ---------------- weight transpose fp32 [K][N] -> bf16 [N][K] ----------------
__global__ void wt_kernel(const float* __restrict__ in, unsigned short* __restrict__ out,
                          int K, int N, int outRowOff, int outLd) {
    __shared__ float tile[32][33];
    int n0 = blockIdx.x * 32, k0 = blockIdx.y * 32;
    int tx = threadIdx.x, ty = threadIdx.y;  // (32,8)
#pragma unroll
    for (int i = 0; i < 4; i++)
        tile[ty + 8 * i][tx] = in[(size_t)(k0 + ty + 8 * i) * N + (n0 + tx)];
    __syncthreads();
#pragma unroll
    for (int i = 0; i < 4; i++)
        out[(size_t)(outRowOff + n0 + ty + 8 * i) * outLd + (k0 + tx)] = f2b(tile[tx][ty + 8 * i]);
}

// ---------------- Wq+Wk transpose (one launch, z selects) -> hi/lo bf16 [1536][768] ----------------
__global__ void wt_split2_kernel(const float* __restrict__ Wq, const float* __restrict__ Wk,
                                 unsigned short* __restrict__ oh, unsigned short* __restrict__ ol) {
    const float* in = blockIdx.z ? Wk : Wq;
    int outRowOff = blockIdx.z * EMBED;
    __shared__ float tile[32][33];
    int n0 = blockIdx.x * 32, k0 = blockIdx.y * 32;
    int tx = threadIdx.x, ty = threadIdx.y;  // (32,8)
#pragma unroll
    for (int i = 0; i < 4; i++)
        tile[ty + 8 * i][tx] = in[(size_t)(k0 + ty + 8 * i) * EMBED + (n0 + tx)];
    __syncthreads();
#pragma unroll
    for (int i = 0; i < 4; i++) {
        float v = tile[tx][ty + 8 * i];
        unsigned short h = f2b(v);
        size_t idx = (size_t)(outRowOff + n0 + ty + 8 * i) * EMBED + (k0 + tx);
        oh[idx] = h;
        ol[idx] = f2b(v - b2f(h));
    }
}

// ---------------- per-batch V transpose: vbuf[row][768] -> VT[768][KPAD], zero k>=577 ----------------
__global__ void vt_kernel(const unsigned short* __restrict__ vbuf, unsigned short* __restrict__ vt) {
    int z = blockIdx.z;
    int d0 = blockIdx.x * 32, c0 = blockIdx.y * 32;
    __shared__ unsigned short tile[32][33];
    int tx = threadIdx.x, ty = threadIdx.y;  // (32,8)
#pragma unroll
    for (int i = 0; i < 4; i++) {
        int c = c0 + ty + 8 * i;
        tile[ty + 8 * i][tx] = (c < SEQ) ? vbuf[((size_t)z * SEQ + c) * EMBED + d0 + tx]
                                         : (unsigned short)0;
    }
    __syncthreads();
#pragma unroll
    for (int i = 0; i < 4; i++) {
        int d = d0 + 8 * i + ty, c = c0 + tx;
        vt[(size_t)z * EMBED * KPAD + (size_t)d * KPAD + c] = tile[tx][ty + 8 * i];
    }
}

// ---------------- GEMM: C = A[M,K] * B^T  (B stored [N,K] row-major, bf16) ----------------
// R7 128x128/BK=64 schedule with B DIRECT FROM GLOBAL (L2-resident panel):
// removes 1/3 of LDS writes and 1/2 of LDS reads (the 4x-redundant B fragments).
// Per wave, a B-frag load covers 16 rows x 64B contiguous across the window's 2 slices
// (full cacheline utilization). A stays LDS-staged (big streaming matrix).
// Requires N % 128 == 0 (all gemm_bt call sites satisfy this).
// EPI 0: bf16; EPI 2: fp32 E[oidx]+acc; EPI 3: bf16 gelu(acc+E[col]); EPI 4: C += acc+E[col]
template <int EPI>
__global__ __launch_bounds__(256, 3) void gemm_bt(
    const unsigned short* __restrict__ A, int lda, long long sA,
    const unsigned short* __restrict__ B, int ldb, long long sB,
    int M, int N, int K,
    void* __restrict__ C, int ldc, long long sC,
    const float* __restrict__ E, long long sE) {
    __shared__ unsigned short As[2][4096];   // [slice][128 rows x 32 k]
    int z = blockIdx.z;
    A += (size_t)z * sA;
    B += (size_t)z * sB;
    int nx = gridDim.x;
    int lin = swz_lin();
    int row0 = (lin / nx) * 128, col0 = (lin % nx) * 128;
    int t = threadIdx.x, l = t & 63, w = t >> 6;
    int wr = w >> 1, wc = w & 1;
    int l15 = l & 15, kb = l >> 4;

    f32x4 acc[4][4] = {};

    int srow = t >> 2;
    int kboff = ((t & 3) ^ ((srow >> 1) & 3)) * 8;

    // hoisted A global element-offsets
    int aoE[2];
#pragma unroll
    for (int c = 0; c < 2; ++c) {
        int ar = row0 + c * 64 + srow; ar = ar < M ? ar : M - 1;
        aoE[c] = ar * lda + kboff;
    }
    // hoisted A LDS fragment offsets
    int aoff[4];
#pragma unroll
    for (int m = 0; m < 4; m++) {
        int r = wr * 64 + m * 16 + l15;
        aoff[m] = r * 32 + (kb ^ ((r >> 1) & 3)) * 8;
    }
    // hoisted B global fragment element-offsets (per n-frag)
    int boG[4];
#pragma unroll
    for (int n = 0; n < 4; n++)
        boG[n] = (col0 + wc * 64 + n * 16 + l15) * ldb + kb * 8;

    auto compute = [&](int sl, const bf16x8* bfr) {
        bf16x8 af[4];
#pragma unroll
        for (int m = 0; m < 4; m++) af[m] = *reinterpret_cast<const bf16x8*>(&As[sl][aoff[m]]);
#pragma unroll
        for (int m = 0; m < 4; m++)
#pragma unroll
            for (int n = 0; n < 4; n++)
                acc[m][n] = __builtin_amdgcn_mfma_f32_16x16x32_bf16(af[m], bfr[n], acc[m][n], 0, 0, 0);
    };

    int ldsoff = t * 8;
    for (int kt = 0; kt < K; kt += 64) {
        gld16(A + (size_t)(aoE[0] + kt), &As[0][ldsoff]);
        gld16(A + (size_t)(aoE[1] + kt), &As[0][2048 + ldsoff]);
        bool has2 = (kt + 32) < K;
        if (has2) {
            gld16(A + (size_t)(aoE[0] + kt + 32), &As[1][ldsoff]);
            gld16(A + (size_t)(aoE[1] + kt + 32), &As[1][2048 + ldsoff]);
        }
        // B fragments direct from global (both slices issued up front)
        bf16x8 bf0[4], bf1[4];
#pragma unroll
        for (int n = 0; n < 4; n++)
            bf0[n] = *reinterpret_cast<const bf16x8*>(B + (size_t)(boG[n] + kt));
        if (has2) {
#pragma unroll
            for (int n = 0; n < 4; n++)
                bf1[n] = *reinterpret_cast<const bf16x8*>(B + (size_t)(boG[n] + kt + 32));
        }
        asm volatile("s_waitcnt vmcnt(0)" ::: "memory");
        __builtin_amdgcn_s_barrier();
        __builtin_amdgcn_sched_barrier(0);
        compute(0, bf0);
        if (has2) compute(1, bf1);
        __builtin_amdgcn_s_barrier();   // reads consumed (MFMA data-dep) -> safe to restage
        __builtin_amdgcn_sched_barrier(0);
    }

    // epilogue: C/D layout col = lane&15, row = (lane>>4)*4 + reg  [m89/m91 verified]
    int rbase = row0 + wr * 64 + (l >> 4) * 4;
    int cbase = col0 + wc * 64 + l15;
    auto epi = [&](bool chk) {
#pragma unroll
        for (int m = 0; m < 4; m++) {
#pragma unroll
            for (int n = 0; n < 4; n++) {
                int col = cbase + n * 16;
#pragma unroll
                for (int j = 0; j < 4; j++) {
                    int row = rbase + m * 16 + j;
                    if (chk && row >= M) continue;
                    float v = acc[m][n][j];
                    size_t oidx = (size_t)z * sC + (size_t)row * ldc + col;
                    if (EPI == 0) {
                        ((unsigned short*)C)[oidx] = f2b(v);
                    } else if (EPI == 2) {
                        ((float*)C)[oidx] = E[oidx] + v;
                    } else if (EPI == 3) {
                        ((unsigned short*)C)[oidx] = f2b(gelu_f(v + E[col]));
                    } else if (EPI == 4) {
                        ((float*)C)[oidx] += v + E[col];
                    }
                }
            }
        }
    };
    if (row0 + 128 <= M) epi(false); else epi(true);
}

// ---------------- High-precision GEMM: (Ah+Al) * (Bh+Bl)^T via 3 MFMA passes ----------------
// B (hi+lo) direct from global (L2-resident); A hi/lo staged in LDS (32KB).
// For ragged N (QKT): B-frag rows may exceed N; reads stay inside the qk allocation
// (regB) and the garbage columns >= N are never stored (epilogue guard) nor read later.
// EPI 0: split-store bf16 hi/lo planes (C, C+planeOff)     (Q,K projection)
// EPI 1: store fp32  2*acc - E[z*sE+col]                   (S scores; E=ksq)
template <int EPI>
__global__ __launch_bounds__(256, 3) void gemm_hp(
    const unsigned short* __restrict__ Ah, const unsigned short* __restrict__ Al, int lda, long long sA,
    const unsigned short* __restrict__ Bh, const unsigned short* __restrict__ Bl, int ldb, long long sB,
    int M, int N, int K,
    void* __restrict__ C, int ldc, long long sC, long long planeOff,
    const float* __restrict__ E, long long sE) {
    __shared__ unsigned short Ash[4096], Asl[4096];
    int z = blockIdx.z;
    Ah += (size_t)z * sA; Al += (size_t)z * sA;
    Bh += (size_t)z * sB; Bl += (size_t)z * sB;
    int nx = gridDim.x;
    int lin = swz_lin();
    int row0 = (lin / nx) * 128, col0 = (lin % nx) * 128;
    int t = threadIdx.x, l = t & 63, w = t >> 6;
    int wr = w >> 1, wc = w & 1;
    int l15 = l & 15, kb = l >> 4;

    f32x4 acc[4][4] = {};

    int srow = t >> 2;
    int kboff = ((t & 3) ^ ((srow >> 1) & 3)) * 8;

    int aoE[2];
#pragma unroll
    for (int c = 0; c < 2; ++c) {
        int ar = row0 + c * 64 + srow; ar = ar < M ? ar : M - 1;
        aoE[c] = ar * lda + kboff;
    }
    int aoff[4];
#pragma unroll
    for (int m = 0; m < 4; m++) {
        int r = wr * 64 + m * 16 + l15;
        aoff[m] = r * 32 + (kb ^ ((r >> 1) & 3)) * 8;
    }
    int boG[4];
#pragma unroll
    for (int n = 0; n < 4; n++)
        boG[n] = (col0 + wc * 64 + n * 16 + l15) * ldb + kb * 8;

    int ldsoff = t * 8;
    for (int kt = 0; kt < K; kt += 32) {
        gld16(Ah + (size_t)(aoE[0] + kt), &Ash[ldsoff]);
        gld16(Ah + (size_t)(aoE[1] + kt), &Ash[2048 + ldsoff]);
        gld16(Al + (size_t)(aoE[0] + kt), &Asl[ldsoff]);
        gld16(Al + (size_t)(aoE[1] + kt), &Asl[2048 + ldsoff]);
        // B hi/lo fragments direct from global
        bf16x8 bfh[4], bfl[4];
#pragma unroll
        for (int n = 0; n < 4; n++) {
            bfh[n] = *reinterpret_cast<const bf16x8*>(Bh + (size_t)(boG[n] + kt));
            bfl[n] = *reinterpret_cast<const bf16x8*>(Bl + (size_t)(boG[n] + kt));
        }
        asm volatile("s_waitcnt vmcnt(0)" ::: "memory");
        __builtin_amdgcn_s_barrier();
        __builtin_amdgcn_sched_barrier(0);
        bf16x8 afh[4], afl[4];
#pragma unroll
        for (int m = 0; m < 4; m++) {
            afh[m] = *reinterpret_cast<const bf16x8*>(&Ash[aoff[m]]);
            afl[m] = *reinterpret_cast<const bf16x8*>(&Asl[aoff[m]]);
        }
#pragma unroll
        for (int m = 0; m < 4; m++)
#pragma unroll
            for (int n = 0; n < 4; n++) {
                acc[m][n] = __builtin_amdgcn_mfma_f32_16x16x32_bf16(afh[m], bfh[n], acc[m][n], 0, 0, 0);
                acc[m][n] = __builtin_amdgcn_mfma_f32_16x16x32_bf16(afh[m], bfl[n], acc[m][n], 0, 0, 0);
                acc[m][n] = __builtin_amdgcn_mfma_f32_16x16x32_bf16(afl[m], bfh[n], acc[m][n], 0, 0, 0);
            }
        __builtin_amdgcn_s_barrier();
        __builtin_amdgcn_sched_barrier(0);
    }

    int rbase = row0 + wr * 64 + (l >> 4) * 4;
    int cbase = col0 + wc * 64 + l15;
    auto epi = [&](bool chk) {
#pragma unroll
        for (int m = 0; m < 4; m++) {
#pragma unroll
            for (int n = 0; n < 4; n++) {
                int col = cbase + n * 16;
                if (chk && col >= N) continue;
#pragma unroll
                for (int j = 0; j < 4; j++) {
                    int row = rbase + m * 16 + j;
                    if (chk && row >= M) continue;
                    float v = acc[m][n][j];
                    size_t oidx = (size_t)z * sC + (size_t)row * ldc + col;
                    if (EPI == 0) {
                        unsigned short h = f2b(v);
                        ((unsigned short*)C)[oidx] = h;
                        ((unsigned short*)C)[oidx + planeOff] = f2b(v - b2f(h));
                    } else if (EPI == 1) {
                        ((float*)C)[oidx] = 2.0f * v - E[(size_t)z * sE + col];
                    }
                }
            }
        }
    };
    if (row0 + 128 <= M && col0 + 128 <= N) epi(false); else epi(true);
}

extern "C" void kernel_launch(void* const* d_in, const int* in_sizes, int n_in,
                              void* d_out, int out_size, void* d_ws, size_t ws_size,
                              hipStream_t stream) {
    const float* x   = (const float*)d_in[0];
    const float* Wq  = (const float*)d_in[1];
    const float* Wk  = (const float*)d_in[2];
    const float* Wv  = (const float*)d_in[3];
    const float* g1  = (const float*)d_in[4];
    const float* be1 = (const float*)d_in[5];
    const float* g2  = (const float*)d_in[6];
    const float* be2 = (const float*)d_in[7];
    const float* W1  = (const float*)d_in[8];
    const float* bb1 = (const float*)d_in[9];
    const float* W2  = (const float*)d_in[10];
    const float* bb2 = (const float*)d_in[11];
    float* out = (float*)d_out;

    char* ws = (char*)d_ws;
    size_t off = 0;
    auto alloc = [&](size_t bytes) -> char* {
        char* p = ws + off;
        off += (bytes + 255) & ~(size_t)255;
        return p;
    };
    unsigned short* wqkTh = (unsigned short*)alloc((size_t)1536 * EMBED * 2);
    unsigned short* wqkTl = (unsigned short*)alloc((size_t)1536 * EMBED * 2);
    unsigned short* wvT   = (unsigned short*)alloc((size_t)EMBED * EMBED * 2);
    unsigned short* w1T   = (unsigned short*)alloc((size_t)HIDDEN * EMBED * 2);
    unsigned short* w2T   = (unsigned short*)alloc((size_t)EMBED * HIDDEN * 2);
    float*          ksqb  = (float*)alloc((size_t)ROWS * 4);
    char* regB = alloc((size_t)ROWS * HIDDEN * 2);
    char* regC = alloc((size_t)2 * ROWS * EMBED * 2);
    unsigned short* vbuf  = (unsigned short*)alloc((size_t)ROWS * EMBED * 2);
    unsigned short* vtb   = (unsigned short*)alloc((size_t)BATCH * EMBED * KPAD * 2);
    unsigned short* Pbuf  = (unsigned short*)alloc((size_t)ROWS * KPAD * 2);
    if (off > ws_size) return;

    unsigned short* qkh  = (unsigned short*)regB;
    unsigned short* qkl  = qkh + (size_t)ROWS * 1536;
    unsigned short* hid  = (unsigned short*)regB;
    unsigned short* h1h  = (unsigned short*)regC;
    unsigned short* h1l  = h1h + (size_t)ROWS * EMBED;
    float*          Sbuf = (float*)regC;
    unsigned short* h2   = (unsigned short*)regC;

    dim3 b256(256), bT(32, 8);

    wt_split2_kernel<<<dim3(24, 24, 2), bT, 0, stream>>>(Wq, Wk, wqkTh, wqkTl);
    wt_kernel<<<dim3(24, 24), bT, 0, stream>>>(Wv, wvT, EMBED, EMBED, 0, EMBED);
    wt_kernel<<<dim3(96, 24), bT, 0, stream>>>(W1, w1T, EMBED, HIDDEN, 0, EMBED);
    wt_kernel<<<dim3(24, 96), bT, 0, stream>>>(W2, w2T, HIDDEN, EMBED, 0, HIDDEN);

    // h1 = LN1(x) -> hi/lo planes
    ln_split_kernel<<<ROWS, b256, 0, stream>>>(x, g1, be1, h1h, h1l);

    // [Q|K] = h1 @ Wqk^T  (high precision, split-stored)
    gemm_hp<0><<<dim3(12, 145, 1), b256, 0, stream>>>(
        h1h, h1l, EMBED, 0, wqkTh, wqkTl, EMBED, 0,
        ROWS, 1536, EMBED, qkh, 1536, 0, (long long)ROWS * 1536, nullptr, 0);

    // V = h1 @ Wv^T
    gemm_bt<0><<<dim3(6, 145, 1), b256, 0, stream>>>(
        h1h, EMBED, 0, wvT, EMBED, 0, ROWS, EMBED, EMBED, vbuf, EMBED, 0, nullptr, 0);

    // ksq from hi/lo K
    ksq_kernel<<<ROWS, b256, 0, stream>>>(qkh, qkl, ksqb);

    // S = 2*Q@K^T - ksq   (batched, high precision)
    gemm_hp<1><<<dim3(5, 5, 32), b256, 0, stream>>>(
        qkh, qkl, 1536, (long long)SEQ * 1536, qkh + EMBED, qkl + EMBED, 1536, (long long)SEQ * 1536,
        SEQ, SEQ, EMBED, Sbuf, SLD, (long long)SEQ * SLD, 0, ksqb, SEQ);

    // P = softmax(S)
    softmax_kernel<<<ROWS, b256, 0, stream>>>(Sbuf, Pbuf);

    // VT per batch
    vt_kernel<<<dim3(24, 19, 32), bT, 0, stream>>>(vbuf, vtb);

    // out = x + P @ V   (batched)
    gemm_bt<2><<<dim3(6, 5, 32), b256, 0, stream>>>(
        Pbuf, KPAD, (long long)SEQ * KPAD, vtb, KPAD, (long long)EMBED * KPAD,
        SEQ, EMBED, KPAD, out, EMBED, (long long)SEQ * EMBED, x, (long long)SEQ * EMBED);

    // h2 = LN2(out)
    ln_kernel<<<ROWS, b256, 0, stream>>>(out, g2, be2, h2);

    // hidden = gelu(h2 @ W1 + b1)
    gemm_bt<3><<<dim3(24, 145, 1), b256, 0, stream>>>(
        h2, EMBED, 0, w1T, EMBED, 0, ROWS, HIDDEN, EMBED, hid, HIDDEN, 0, bb1, 0);

    // out += hidden @ W2 + b2
    gemm_bt<4><<<dim3(6, 145, 1), b256, 0, stream>>>(
        hid, HIDDEN, 0, w2T, HIDDEN, 0, ROWS, EMBED, HIDDEN, out, EMBED, 0, bb2, 0);
}

// Round 12
// 740.524 us; speedup vs baseline: 1.4317x; 1.4317x over previous
//
#include <hip/hip_runtime.h>

#define EMBED 768
#define HIDDEN 3072
#define SEQ 577
#define BATCH 32
#define ROWS (BATCH*SEQ)      /* 18464 */
#define KPAD 608              /* padded seq for PV K-dim (19*32) */
#define SLD 640               /* S row stride in floats */

typedef __attribute__((ext_vector_type(4))) float f32x4;
typedef __attribute__((ext_vector_type(8))) __bf16 bf16x8;
typedef unsigned int __attribute__((address_space(1))) as1_u32;
typedef unsigned int __attribute__((address_space(3))) as3_u32;

__device__ __forceinline__ unsigned short f2b(float f) {
    unsigned int u = __float_as_uint(f);
    u = u + 0x7FFFu + ((u >> 16) & 1u);   // round-to-nearest-even
    return (unsigned short)(u >> 16);
}
__device__ __forceinline__ float b2f(unsigned short s) {
    return __uint_as_float(((unsigned int)s) << 16);
}
__device__ __forceinline__ void gld16(const unsigned short* g, unsigned short* l) {
    __builtin_amdgcn_global_load_lds((const as1_u32*)g, (as3_u32*)l, 16, 0, 0);
}
// tanh-form GELU (max err vs exact-erf < 1e-3, below bf16 quantization of hid)
__device__ __forceinline__ float gelu_f(float x) {
    float u = x * (0.7978845608028654f + 0.03567740814183f * x * x);
    float e = __expf(2.0f * u);                 // +inf-safe
    float th = 1.0f - 2.0f / (e + 1.0f);
    return 0.5f * x * (1.0f + th);
}

// grid decomposition: x = col-block, y = row-block; chunked-bijective XCD swizzle (m204)
__device__ __forceinline__ int swz_lin() {
    int nx = gridDim.x;
    int lin = blockIdx.y * nx + blockIdx.x;
    if (gridDim.z == 1) {
        int nwg = nx * gridDim.y;
        int q = nwg >> 3, r = nwg & 7;
        int xcd = lin & 7, blk = lin >> 3;
        lin = (xcd < r ? xcd * (q + 1) : r * (q + 1) + (xcd - r) * q) + blk;
    }
    return lin;
}

// ---------------- LayerNorm: fp32 row -> bf16 row ----------------
__global__ void ln_kernel(const float* __restrict__ x, const float* __restrict__ g,
                          const float* __restrict__ b, unsigned short* __restrict__ o) {
    int row = blockIdx.x;
    const float* xr = x + (size_t)row * EMBED;
    int t = threadIdx.x;
    float v0 = xr[t], v1 = xr[t + 256], v2 = xr[t + 512];
    float s = v0 + v1 + v2;
    float ss = v0 * v0 + v1 * v1 + v2 * v2;
#pragma unroll
    for (int d = 32; d; d >>= 1) { s += __shfl_down(s, d); ss += __shfl_down(ss, d); }
    __shared__ float rs[4], rss[4];
    if ((t & 63) == 0) { rs[t >> 6] = s; rss[t >> 6] = ss; }
    __syncthreads();
    s = rs[0] + rs[1] + rs[2] + rs[3];
    ss = rss[0] + rss[1] + rss[2] + rss[3];
    float mu = s * (1.0f / EMBED);
    float var = ss * (1.0f / EMBED) - mu * mu;
    float rstd = rsqrtf(var + 1e-5f);
    unsigned short* orow = o + (size_t)row * EMBED;
    orow[t]       = f2b((v0 - mu) * rstd * g[t]       + b[t]);
    orow[t + 256] = f2b((v1 - mu) * rstd * g[t + 256] + b[t + 256]);
    orow[t + 512] = f2b((v2 - mu) * rstd * g[t + 512] + b[t + 512]);
}

// ---------------- LayerNorm -> hi/lo bf16 planes ----------------
__global__ void ln_split_kernel(const float* __restrict__ x, const float* __restrict__ g,
                                const float* __restrict__ b, unsigned short* __restrict__ oh,
                                unsigned short* __restrict__ ol) {
    int row = blockIdx.x;
    const float* xr = x + (size_t)row * EMBED;
    int t = threadIdx.x;
    float v0 = xr[t], v1 = xr[t + 256], v2 = xr[t + 512];
    float s = v0 + v1 + v2;
    float ss = v0 * v0 + v1 * v1 + v2 * v2;
#pragma unroll
    for (int d = 32; d; d >>= 1) { s += __shfl_down(s, d); ss += __shfl_down(ss, d); }
    __shared__ float rs[4], rss[4];
    if ((t & 63) == 0) { rs[t >> 6] = s; rss[t >> 6] = ss; }
    __syncthreads();
    s = rs[0] + rs[1] + rs[2] + rs[3];
    ss = rss[0] + rss[1] + rss[2] + rss[3];
    float mu = s * (1.0f / EMBED);
    float var = ss * (1.0f / EMBED) - mu * mu;
    float rstd = rsqrtf(var + 1e-5f);
    size_t base = (size_t)row * EMBED;
#pragma unroll
    for (int i = 0; i < 3; i++) {
        int d = t + 256 * i;
        float v = (i == 0 ? v0 : (i == 1 ? v1 : v2));
        float y = (v - mu) * rstd * g[d] + b[d];
        unsigned short h = f2b(y);
        oh[base + d] = h;
        ol[base + d] = f2b(y - b2f(h));
    }
}

// ---------------- ksq: per-row sum of K^2 from hi/lo planes (cols 768..1535) ----------------
__global__ void ksq_kernel(const unsigned short* __restrict__ qh,
                           const unsigned short* __restrict__ ql, float* __restrict__ ksq) {
    int row = blockIdx.x;
    int t = threadIdx.x;
    size_t base = (size_t)row * 1536 + EMBED;
    float s = 0.f;
#pragma unroll
    for (int i = 0; i < 3; i++) {
        int d = t + 256 * i;
        float k = b2f(qh[base + d]) + b2f(ql[base + d]);
        s += k * k;
    }
#pragma unroll
    for (int d = 32; d; d >>= 1) s += __shfl_down(s, d);
    __shared__ float rs[4];
    if ((t & 63) == 0) rs[t >> 6] = s;
    __syncthreads();
    if (t == 0) ksq[row] = rs[0] + rs[1] + rs[2] + rs[3];
}

// ---------------- row softmax of (S) -> bf16 P, zero-padded to KPAD ----------------
__global__ void softmax_kernel(const float* __restrict__ S, unsigned short* __restrict__ P) {
    int r = blockIdx.x;
    int t = threadIdx.x;
    const float* sr = S + (size_t)r * SLD;
    float v0 = sr[t];
    float v1 = sr[t + 256];
    float v2 = (t + 512 < SEQ) ? sr[t + 512] : -3.0e38f;
    float m = fmaxf(v0, fmaxf(v1, v2));
#pragma unroll
    for (int d = 32; d; d >>= 1) m = fmaxf(m, __shfl_down(m, d));
    __shared__ float rm[4];
    if ((t & 63) == 0) rm[t >> 6] = m;
    __syncthreads();
    m = fmaxf(fmaxf(rm[0], rm[1]), fmaxf(rm[2], rm[3]));
    float e0 = __expf(v0 - m);
    float e1 = __expf(v1 - m);
    float e2 = (t + 512 < SEQ) ? __expf(v2 - m) : 0.0f;
    float s = e0 + e1 + e2;
#pragma unroll
    for (int d = 32; d; d >>= 1) s += __shfl_down(s, d);
    __shared__ float rsum[4];
    if ((t & 63) == 0) rsum[t >> 6] = s;
    __syncthreads();
    float inv = 1.0f / (rsum[0] + rsum[1] + rsum[2] + rsum[3]);
    unsigned short* pr = P + (size_t)r * KPAD;
    pr[t]       = f2b(e0 * inv);
    pr[t + 256] = f2b(e1 * inv);
    if (t + 512 < KPAD) pr[t + 512] = f2b(e2 * inv);   // zeros for 577..607
}

// ---------------- weight transpose fp32 [K][N] -> bf16 [N][K] ----------------
__global__ void wt_kernel(const float* __restrict__ in, unsigned short* __restrict__ out,
                          int K, int N, int outRowOff, int outLd) {
    __shared__ float tile[32][33];
    int n0 = blockIdx.x * 32, k0 = blockIdx.y * 32;
    int tx = threadIdx.x, ty = threadIdx.y;  // (32,8)
#pragma unroll
    for (int i = 0; i < 4; i++)
        tile[ty + 8 * i][tx] = in[(size_t)(k0 + ty + 8 * i) * N + (n0 + tx)];
    __syncthreads();
#pragma unroll
    for (int i = 0; i < 4; i++)
        out[(size_t)(outRowOff + n0 + ty + 8 * i) * outLd + (k0 + tx)] = f2b(tile[tx][ty + 8 * i]);
}

// ---------------- Wq+Wk transpose (one launch, z selects) -> hi/lo bf16 [1536][768] ----------------
__global__ void wt_split2_kernel(const float* __restrict__ Wq, const float* __restrict__ Wk,
                                 unsigned short* __restrict__ oh, unsigned short* __restrict__ ol) {
    const float* in = blockIdx.z ? Wk : Wq;
    int outRowOff = blockIdx.z * EMBED;
    __shared__ float tile[32][33];
    int n0 = blockIdx.x * 32, k0 = blockIdx.y * 32;
    int tx = threadIdx.x, ty = threadIdx.y;  // (32,8)
#pragma unroll
    for (int i = 0; i < 4; i++)
        tile[ty + 8 * i][tx] = in[(size_t)(k0 + ty + 8 * i) * EMBED + (n0 + tx)];
    __syncthreads();
#pragma unroll
    for (int i = 0; i < 4; i++) {
        float v = tile[tx][ty + 8 * i];
        unsigned short h = f2b(v);
        size_t idx = (size_t)(outRowOff + n0 + ty + 8 * i) * EMBED + (k0 + tx);
        oh[idx] = h;
        ol[idx] = f2b(v - b2f(h));
    }
}

// ---------------- per-batch V transpose: vbuf[row][768] -> VT[768][KPAD], zero k>=577 ----------------
__global__ void vt_kernel(const unsigned short* __restrict__ vbuf, unsigned short* __restrict__ vt) {
    int z = blockIdx.z;
    int d0 = blockIdx.x * 32, c0 = blockIdx.y * 32;
    __shared__ unsigned short tile[32][33];
    int tx = threadIdx.x, ty = threadIdx.y;  // (32,8)
#pragma unroll
    for (int i = 0; i < 4; i++) {
        int c = c0 + ty + 8 * i;
        tile[ty + 8 * i][tx] = (c < SEQ) ? vbuf[((size_t)z * SEQ + c) * EMBED + d0 + tx]
                                         : (unsigned short)0;
    }
    __syncthreads();
#pragma unroll
    for (int i = 0; i < 4; i++) {
        int d = d0 + 8 * i + ty, c = c0 + tx;
        vt[(size_t)z * EMBED * KPAD + (size_t)d * KPAD + c] = tile[tx][ty + 8 * i];
    }
}

// ---------------- GEMM (R7-exact): 128x128, 256 thr, BK=64 single-buffer two-slice ----------------
// EPI 0: bf16; EPI 2: fp32 E[oidx]+acc; EPI 3: bf16 gelu(acc+E[col]); EPI 4: C += acc+E[col]
template <int EPI>
__global__ __launch_bounds__(256, 2) void gemm_bt(
    const unsigned short* __restrict__ A, int lda, long long sA,
    const unsigned short* __restrict__ B, int ldb, long long sB,
    int M, int N, int K,
    void* __restrict__ C, int ldc, long long sC,
    const float* __restrict__ E, long long sE) {
    __shared__ unsigned short As[2][4096];   // [slice][128 rows x 32 k]
    __shared__ unsigned short Bs[2][4096];
    int z = blockIdx.z;
    A += (size_t)z * sA;
    B += (size_t)z * sB;
    int nx = gridDim.x;
    int lin = swz_lin();
    int row0 = (lin / nx) * 128, col0 = (lin % nx) * 128;
    int t = threadIdx.x, l = t & 63, w = t >> 6;
    int wr = w >> 1, wc = w & 1;
    int l15 = l & 15, kb = l >> 4;

    f32x4 acc[4][4] = {};

    int srow = t >> 2;
    int kboff = ((t & 3) ^ ((srow >> 1) & 3)) * 8;

    // hoisted global element-offsets (32-bit; all tensors < 2^31 elements)
    int aoE[2], boE[2];
#pragma unroll
    for (int c = 0; c < 2; ++c) {
        int ar = row0 + c * 64 + srow; ar = ar < M ? ar : M - 1;
        aoE[c] = ar * lda + kboff;
        int br = col0 + c * 64 + srow; br = br < N ? br : N - 1;
        boE[c] = br * ldb + kboff;
    }
    // hoisted LDS fragment element-offsets
    int aoff[4], boff[4];
#pragma unroll
    for (int m = 0; m < 4; m++) {
        int r = wr * 64 + m * 16 + l15;
        aoff[m] = r * 32 + (kb ^ ((r >> 1) & 3)) * 8;
        int rn = wc * 64 + m * 16 + l15;
        boff[m] = rn * 32 + (kb ^ ((rn >> 1) & 3)) * 8;
    }

    auto compute = [&](int sl) {
        bf16x8 af[4], bfr[4];
#pragma unroll
        for (int m = 0; m < 4; m++) af[m] = *reinterpret_cast<const bf16x8*>(&As[sl][aoff[m]]);
#pragma unroll
        for (int n = 0; n < 4; n++) bfr[n] = *reinterpret_cast<const bf16x8*>(&Bs[sl][boff[n]]);
#pragma unroll
        for (int m = 0; m < 4; m++)
#pragma unroll
            for (int n = 0; n < 4; n++)
                acc[m][n] = __builtin_amdgcn_mfma_f32_16x16x32_bf16(af[m], bfr[n], acc[m][n], 0, 0, 0);
    };

    int ldsoff = t * 8;
    for (int kt = 0; kt < K; kt += 64) {
        gld16(A + (size_t)(aoE[0] + kt), &As[0][ldsoff]);
        gld16(A + (size_t)(aoE[1] + kt), &As[0][2048 + ldsoff]);
        gld16(B + (size_t)(boE[0] + kt), &Bs[0][ldsoff]);
        gld16(B + (size_t)(boE[1] + kt), &Bs[0][2048 + ldsoff]);
        bool has2 = (kt + 32) < K;
        if (has2) {
            gld16(A + (size_t)(aoE[0] + kt + 32), &As[1][ldsoff]);
            gld16(A + (size_t)(aoE[1] + kt + 32), &As[1][2048 + ldsoff]);
            gld16(B + (size_t)(boE[0] + kt + 32), &Bs[1][ldsoff]);
            gld16(B + (size_t)(boE[1] + kt + 32), &Bs[1][2048 + ldsoff]);
        }
        asm volatile("s_waitcnt vmcnt(0)" ::: "memory");
        __builtin_amdgcn_s_barrier();
        __builtin_amdgcn_sched_barrier(0);
        compute(0);
        if (has2) compute(1);
        __builtin_amdgcn_s_barrier();   // reads consumed (MFMA data-dep) -> safe to restage
        __builtin_amdgcn_sched_barrier(0);
    }

    // epilogue: C/D layout col = lane&15, row = (lane>>4)*4 + reg  [m89/m91 verified]
    int rbase = row0 + wr * 64 + (l >> 4) * 4;
    int cbase = col0 + wc * 64 + l15;
    auto epi = [&](bool chk) {
#pragma unroll
        for (int m = 0; m < 4; m++) {
#pragma unroll
            for (int n = 0; n < 4; n++) {
                int col = cbase + n * 16;
                if (chk && col >= N) continue;
#pragma unroll
                for (int j = 0; j < 4; j++) {
                    int row = rbase + m * 16 + j;
                    if (chk && row >= M) continue;
                    float v = acc[m][n][j];
                    size_t oidx = (size_t)z * sC + (size_t)row * ldc + col;
                    if (EPI == 0) {
                        ((unsigned short*)C)[oidx] = f2b(v);
                    } else if (EPI == 2) {
                        ((float*)C)[oidx] = E[oidx] + v;
                    } else if (EPI == 3) {
                        ((unsigned short*)C)[oidx] = f2b(gelu_f(v + E[col]));
                    } else if (EPI == 4) {
                        ((float*)C)[oidx] += v + E[col];
                    }
                }
            }
        }
    };
    if (row0 + 128 <= M && col0 + 128 <= N) epi(false); else epi(true);
}

// ---------------- High-precision GEMM (R10-exact): 256x128, 512 thr, BK=32, LDS 48KB ----------------
// (Ah+Al)*(Bh+Bl)^T via 3 MFMA passes.
// EPI 0: split-store bf16 hi/lo planes (C, C+planeOff)     (Q,K projection)
// EPI 1: store fp32  2*acc - E[z*sE+col]                   (S scores; E=ksq)
template <int EPI>
__global__ __launch_bounds__(512, 2) void gemm_hp(
    const unsigned short* __restrict__ Ah, const unsigned short* __restrict__ Al, int lda, long long sA,
    const unsigned short* __restrict__ Bh, const unsigned short* __restrict__ Bl, int ldb, long long sB,
    int M, int N, int K,
    void* __restrict__ C, int ldc, long long sC, long long planeOff,
    const float* __restrict__ E, long long sE) {
    __shared__ unsigned short Ash[8192], Asl[8192], Bsh[4096], Bsl[4096];
    int z = blockIdx.z;
    Ah += (size_t)z * sA; Al += (size_t)z * sA;
    Bh += (size_t)z * sB; Bl += (size_t)z * sB;
    int nx = gridDim.x;
    int lin = swz_lin();
    int row0 = (lin / nx) * 256, col0 = (lin % nx) * 128;
    int t = threadIdx.x, l = t & 63, w = t >> 6;
    int wr = w >> 1, wc = w & 1;
    int l15 = l & 15, kb = l >> 4;

    f32x4 acc[4][4] = {};

    int srow = t >> 2;
    int kboff = ((t & 3) ^ ((srow >> 1) & 3)) * 8;

    int aoE[2], boE;
#pragma unroll
    for (int c = 0; c < 2; ++c) {
        int ar = row0 + c * 128 + srow; ar = ar < M ? ar : M - 1;
        aoE[c] = ar * lda + kboff;
    }
    {
        int br = col0 + srow; br = br < N ? br : N - 1;
        boE = br * ldb + kboff;
    }
    int aoff[4], boff[4];
#pragma unroll
    for (int m = 0; m < 4; m++) {
        int r = wr * 64 + m * 16 + l15;
        aoff[m] = r * 32 + (kb ^ ((r >> 1) & 3)) * 8;
        int rn = wc * 64 + m * 16 + l15;
        boff[m] = rn * 32 + (kb ^ ((rn >> 1) & 3)) * 8;
    }

    int ldsoff = t * 8;
    for (int kt = 0; kt < K; kt += 32) {
        gld16(Ah + (size_t)(aoE[0] + kt), &Ash[ldsoff]);
        gld16(Ah + (size_t)(aoE[1] + kt), &Ash[4096 + ldsoff]);
        gld16(Al + (size_t)(aoE[0] + kt), &Asl[ldsoff]);
        gld16(Al + (size_t)(aoE[1] + kt), &Asl[4096 + ldsoff]);
        gld16(Bh + (size_t)(boE + kt), &Bsh[ldsoff]);
        gld16(Bl + (size_t)(boE + kt), &Bsl[ldsoff]);
        __syncthreads();
        bf16x8 afh[4], afl[4], bfh[4], bfl[4];
#pragma unroll
        for (int m = 0; m < 4; m++) {
            afh[m] = *reinterpret_cast<const bf16x8*>(&Ash[aoff[m]]);
            afl[m] = *reinterpret_cast<const bf16x8*>(&Asl[aoff[m]]);
        }
#pragma unroll
        for (int n = 0; n < 4; n++) {
            bfh[n] = *reinterpret_cast<const bf16x8*>(&Bsh[boff[n]]);
            bfl[n] = *reinterpret_cast<const bf16x8*>(&Bsl[boff[n]]);
        }
#pragma unroll
        for (int m = 0; m < 4; m++)
#pragma unroll
            for (int n = 0; n < 4; n++) {
                acc[m][n] = __builtin_amdgcn_mfma_f32_16x16x32_bf16(afh[m], bfh[n], acc[m][n], 0, 0, 0);
                acc[m][n] = __builtin_amdgcn_mfma_f32_16x16x32_bf16(afh[m], bfl[n], acc[m][n], 0, 0, 0);
                acc[m][n] = __builtin_amdgcn_mfma_f32_16x16x32_bf16(afl[m], bfh[n], acc[m][n], 0, 0, 0);
            }
        __syncthreads();
    }

    int rbase = row0 + wr * 64 + (l >> 4) * 4;
    int cbase = col0 + wc * 64 + l15;
    auto epi = [&](bool chk) {
#pragma unroll
        for (int m = 0; m < 4; m++) {
#pragma unroll
            for (int n = 0; n < 4; n++) {
                int col = cbase + n * 16;
                if (chk && col >= N) continue;
#pragma unroll
                for (int j = 0; j < 4; j++) {
                    int row = rbase + m * 16 + j;
                    if (chk && row >= M) continue;
                    float v = acc[m][n][j];
                    size_t oidx = (size_t)z * sC + (size_t)row * ldc + col;
                    if (EPI == 0) {
                        unsigned short h = f2b(v);
                        ((unsigned short*)C)[oidx] = h;
                        ((unsigned short*)C)[oidx + planeOff] = f2b(v - b2f(h));
                    } else if (EPI == 1) {
                        ((float*)C)[oidx] = 2.0f * v - E[(size_t)z * sE + col];
                    }
                }
            }
        }
    };
    if (row0 + 256 <= M && col0 + 128 <= N) epi(false); else epi(true);
}

extern "C" void kernel_launch(void* const* d_in, const int* in_sizes, int n_in,
                              void* d_out, int out_size, void* d_ws, size_t ws_size,
                              hipStream_t stream) {
    const float* x   = (const float*)d_in[0];
    const float* Wq  = (const float*)d_in[1];
    const float* Wk  = (const float*)d_in[2];
    const float* Wv  = (const float*)d_in[3];
    const float* g1  = (const float*)d_in[4];
    const float* be1 = (const float*)d_in[5];
    const float* g2  = (const float*)d_in[6];
    const float* be2 = (const float*)d_in[7];
    const float* W1  = (const float*)d_in[8];
    const float* bb1 = (const float*)d_in[9];
    const float* W2  = (const float*)d_in[10];
    const float* bb2 = (const float*)d_in[11];
    float* out = (float*)d_out;

    char* ws = (char*)d_ws;
    size_t off = 0;
    auto alloc = [&](size_t bytes) -> char* {
        char* p = ws + off;
        off += (bytes + 255) & ~(size_t)255;
        return p;
    };
    unsigned short* wqkTh = (unsigned short*)alloc((size_t)1536 * EMBED * 2);
    unsigned short* wqkTl = (unsigned short*)alloc((size_t)1536 * EMBED * 2);
    unsigned short* wvT   = (unsigned short*)alloc((size_t)EMBED * EMBED * 2);
    unsigned short* w1T   = (unsigned short*)alloc((size_t)HIDDEN * EMBED * 2);
    unsigned short* w2T   = (unsigned short*)alloc((size_t)EMBED * HIDDEN * 2);
    float*          ksqb  = (float*)alloc((size_t)ROWS * 4);
    char* regB = alloc((size_t)ROWS * HIDDEN * 2);
    char* regC = alloc((size_t)2 * ROWS * EMBED * 2);
    unsigned short* vbuf  = (unsigned short*)alloc((size_t)ROWS * EMBED * 2);
    unsigned short* vtb   = (unsigned short*)alloc((size_t)BATCH * EMBED * KPAD * 2);
    unsigned short* Pbuf  = (unsigned short*)alloc((size_t)ROWS * KPAD * 2);
    if (off > ws_size) return;

    unsigned short* qkh  = (unsigned short*)regB;
    unsigned short* qkl  = qkh + (size_t)ROWS * 1536;
    unsigned short* hid  = (unsigned short*)regB;
    unsigned short* h1h  = (unsigned short*)regC;
    unsigned short* h1l  = h1h + (size_t)ROWS * EMBED;
    float*          Sbuf = (float*)regC;
    unsigned short* h2   = (unsigned short*)regC;

    dim3 b256(256), b512(512), bT(32, 8);

    wt_split2_kernel<<<dim3(24, 24, 2), bT, 0, stream>>>(Wq, Wk, wqkTh, wqkTl);
    wt_kernel<<<dim3(24, 24), bT, 0, stream>>>(Wv, wvT, EMBED, EMBED, 0, EMBED);
    wt_kernel<<<dim3(96, 24), bT, 0, stream>>>(W1, w1T, EMBED, HIDDEN, 0, EMBED);
    wt_kernel<<<dim3(24, 96), bT, 0, stream>>>(W2, w2T, HIDDEN, EMBED, 0, HIDDEN);

    // h1 = LN1(x) -> hi/lo planes
    ln_split_kernel<<<ROWS, b256, 0, stream>>>(x, g1, be1, h1h, h1l);

    // [Q|K] = h1 @ Wqk^T  (high precision, split-stored)  256x128 tiles
    gemm_hp<0><<<dim3(12, 73, 1), b512, 0, stream>>>(
        h1h, h1l, EMBED, 0, wqkTh, wqkTl, EMBED, 0,
        ROWS, 1536, EMBED, qkh, 1536, 0, (long long)ROWS * 1536, nullptr, 0);

    // V = h1 @ Wv^T   (128^2 / 256thr)
    gemm_bt<0><<<dim3(6, 145, 1), b256, 0, stream>>>(
        h1h, EMBED, 0, wvT, EMBED, 0, ROWS, EMBED, EMBED, vbuf, EMBED, 0, nullptr, 0);

    // ksq from hi/lo K
    ksq_kernel<<<ROWS, b256, 0, stream>>>(qkh, qkl, ksqb);

    // S = 2*Q@K^T - ksq   (batched, high precision, 256x128 tiles)
    gemm_hp<1><<<dim3(5, 3, 32), b512, 0, stream>>>(
        qkh, qkl, 1536, (long long)SEQ * 1536, qkh + EMBED, qkl + EMBED, 1536, (long long)SEQ * 1536,
        SEQ, SEQ, EMBED, Sbuf, SLD, (long long)SEQ * SLD, 0, ksqb, SEQ);

    // P = softmax(S)
    softmax_kernel<<<ROWS, b256, 0, stream>>>(Sbuf, Pbuf);

    // VT per batch
    vt_kernel<<<dim3(24, 19, 32), bT, 0, stream>>>(vbuf, vtb);

    // out = x + P @ V   (batched, 128^2 / 256thr)
    gemm_bt<2><<<dim3(6, 5, 32), b256, 0, stream>>>(
        Pbuf, KPAD, (long long)SEQ * KPAD, vtb, KPAD, (long long)EMBED * KPAD,
        SEQ, EMBED, KPAD, out, EMBED, (long long)SEQ * EMBED, x, (long long)SEQ * EMBED);

    // h2 = LN2(out)
    ln_kernel<<<ROWS, b256, 0, stream>>>(out, g2, be2, h2);

    // hidden = gelu(h2 @ W1 + b1)   (128^2 / 256thr)
    gemm_bt<3><<<dim3(24, 145, 1), b256, 0, stream>>>(
        h2, EMBED, 0, w1T, EMBED, 0, ROWS, HIDDEN, EMBED, hid, HIDDEN, 0, bb1, 0);

    // out += hidden @ W2 + b2       (128^2 / 256thr)
    gemm_bt<4><<<dim3(6, 145, 1), b256, 0, stream>>>(
        hid, HIDDEN, 0, w2T, HIDDEN, 0, ROWS, EMBED, HIDDEN, out, EMBED, 0, bb2, 0);
}

// Round 13
// 723.092 us; speedup vs baseline: 1.4662x; 1.0241x over previous
//
#include <hip/hip_runtime.h>

#define EMBED 768
#define HIDDEN 3072
#define SEQ 577
#define BATCH 32
#define ROWS (BATCH*SEQ)      /* 18464 */
#define KPAD 608              /* padded seq for PV K-dim (19*32) */
#define SLD 640               /* S row stride in floats */

typedef __attribute__((ext_vector_type(4))) float f32x4;
typedef __attribute__((ext_vector_type(8))) __bf16 bf16x8;
typedef unsigned int __attribute__((address_space(1))) as1_u32;
typedef unsigned int __attribute__((address_space(3))) as3_u32;

__device__ __forceinline__ unsigned short f2b(float f) {
    unsigned int u = __float_as_uint(f);
    u = u + 0x7FFFu + ((u >> 16) & 1u);   // round-to-nearest-even
    return (unsigned short)(u >> 16);
}
__device__ __forceinline__ float b2f(unsigned short s) {
    return __uint_as_float(((unsigned int)s) << 16);
}
__device__ __forceinline__ void gld16(const unsigned short* g, unsigned short* l) {
    __builtin_amdgcn_global_load_lds((const as1_u32*)g, (as3_u32*)l, 16, 0, 0);
}
// tanh-form GELU (max err vs exact-erf < 1e-3, below bf16 quantization of hid)
__device__ __forceinline__ float gelu_f(float x) {
    float u = x * (0.7978845608028654f + 0.03567740814183f * x * x);
    float e = __expf(2.0f * u);                 // +inf-safe
    float th = 1.0f - 2.0f / (e + 1.0f);
    return 0.5f * x * (1.0f + th);
}

// grid decomposition: x = col-block, y = row-block; chunked-bijective XCD swizzle (m204)
__device__ __forceinline__ int swz_lin() {
    int nx = gridDim.x;
    int lin = blockIdx.y * nx + blockIdx.x;
    if (gridDim.z == 1) {
        int nwg = nx * gridDim.y;
        int q = nwg >> 3, r = nwg & 7;
        int xcd = lin & 7, blk = lin >> 3;
        lin = (xcd < r ? xcd * (q + 1) : r * (q + 1) + (xcd - r) * q) + blk;
    }
    return lin;
}

// ---------------- LayerNorm: fp32 row -> bf16 row ----------------
__global__ void ln_kernel(const float* __restrict__ x, const float* __restrict__ g,
                          const float* __restrict__ b, unsigned short* __restrict__ o) {
    int row = blockIdx.x;
    const float* xr = x + (size_t)row * EMBED;
    int t = threadIdx.x;
    float v0 = xr[t], v1 = xr[t + 256], v2 = xr[t + 512];
    float s = v0 + v1 + v2;
    float ss = v0 * v0 + v1 * v1 + v2 * v2;
#pragma unroll
    for (int d = 32; d; d >>= 1) { s += __shfl_down(s, d); ss += __shfl_down(ss, d); }
    __shared__ float rs[4], rss[4];
    if ((t & 63) == 0) { rs[t >> 6] = s; rss[t >> 6] = ss; }
    __syncthreads();
    s = rs[0] + rs[1] + rs[2] + rs[3];
    ss = rss[0] + rss[1] + rss[2] + rss[3];
    float mu = s * (1.0f / EMBED);
    float var = ss * (1.0f / EMBED) - mu * mu;
    float rstd = rsqrtf(var + 1e-5f);
    unsigned short* orow = o + (size_t)row * EMBED;
    orow[t]       = f2b((v0 - mu) * rstd * g[t]       + b[t]);
    orow[t + 256] = f2b((v1 - mu) * rstd * g[t + 256] + b[t + 256]);
    orow[t + 512] = f2b((v2 - mu) * rstd * g[t + 512] + b[t + 512]);
}

// ---------------- LayerNorm -> hi/lo bf16 planes ----------------
__global__ void ln_split_kernel(const float* __restrict__ x, const float* __restrict__ g,
                                const float* __restrict__ b, unsigned short* __restrict__ oh,
                                unsigned short* __restrict__ ol) {
    int row = blockIdx.x;
    const float* xr = x + (size_t)row * EMBED;
    int t = threadIdx.x;
    float v0 = xr[t], v1 = xr[t + 256], v2 = xr[t + 512];
    float s = v0 + v1 + v2;
    float ss = v0 * v0 + v1 * v1 + v2 * v2;
#pragma unroll
    for (int d = 32; d; d >>= 1) { s += __shfl_down(s, d); ss += __shfl_down(ss, d); }
    __shared__ float rs[4], rss[4];
    if ((t & 63) == 0) { rs[t >> 6] = s; rss[t >> 6] = ss; }
    __syncthreads();
    s = rs[0] + rs[1] + rs[2] + rs[3];
    ss = rss[0] + rss[1] + rss[2] + rss[3];
    float mu = s * (1.0f / EMBED);
    float var = ss * (1.0f / EMBED) - mu * mu;
    float rstd = rsqrtf(var + 1e-5f);
    size_t base = (size_t)row * EMBED;
#pragma unroll
    for (int i = 0; i < 3; i++) {
        int d = t + 256 * i;
        float v = (i == 0 ? v0 : (i == 1 ? v1 : v2));
        float y = (v - mu) * rstd * g[d] + b[d];
        unsigned short h = f2b(y);
        oh[base + d] = h;
        ol[base + d] = f2b(y - b2f(h));
    }
}

// ---------------- ksq: per-row sum of K^2 from hi/lo planes (cols 768..1535) ----------------
__global__ void ksq_kernel(const unsigned short* __restrict__ qh,
                           const unsigned short* __restrict__ ql, float* __restrict__ ksq) {
    int row = blockIdx.x;
    int t = threadIdx.x;
    size_t base = (size_t)row * 1536 + EMBED;
    float s = 0.f;
#pragma unroll
    for (int i = 0; i < 3; i++) {
        int d = t + 256 * i;
        float k = b2f(qh[base + d]) + b2f(ql[base + d]);
        s += k * k;
    }
#pragma unroll
    for (int d = 32; d; d >>= 1) s += __shfl_down(s, d);
    __shared__ float rs[4];
    if ((t & 63) == 0) rs[t >> 6] = s;
    __syncthreads();
    if (t == 0) ksq[row] = rs[0] + rs[1] + rs[2] + rs[3];
}

// ---------------- row softmax of (S) -> bf16 P, zero-padded to KPAD ----------------
__global__ void softmax_kernel(const float* __restrict__ S, unsigned short* __restrict__ P) {
    int r = blockIdx.x;
    int t = threadIdx.x;
    const float* sr = S + (size_t)r * SLD;
    float v0 = sr[t];
    float v1 = sr[t + 256];
    float v2 = (t + 512 < SEQ) ? sr[t + 512] : -3.0e38f;
    float m = fmaxf(v0, fmaxf(v1, v2));
#pragma unroll
    for (int d = 32; d; d >>= 1) m = fmaxf(m, __shfl_down(m, d));
    __shared__ float rm[4];
    if ((t & 63) == 0) rm[t >> 6] = m;
    __syncthreads();
    m = fmaxf(fmaxf(rm[0], rm[1]), fmaxf(rm[2], rm[3]));
    float e0 = __expf(v0 - m);
    float e1 = __expf(v1 - m);
    float e2 = (t + 512 < SEQ) ? __expf(v2 - m) : 0.0f;
    float s = e0 + e1 + e2;
#pragma unroll
    for (int d = 32; d; d >>= 1) s += __shfl_down(s, d);
    __shared__ float rsum[4];
    if ((t & 63) == 0) rsum[t >> 6] = s;
    __syncthreads();
    float inv = 1.0f / (rsum[0] + rsum[1] + rsum[2] + rsum[3]);
    unsigned short* pr = P + (size_t)r * KPAD;
    pr[t]       = f2b(e0 * inv);
    pr[t + 256] = f2b(e1 * inv);
    if (t + 512 < KPAD) pr[t + 512] = f2b(e2 * inv);   // zeros for 577..607
}

// ---------------- weight transpose fp32 [K][N] -> bf16 [N][K] ----------------
__global__ void wt_kernel(const float* __restrict__ in, unsigned short* __restrict__ out,
                          int K, int N, int outRowOff, int outLd) {
    __shared__ float tile[32][33];
    int n0 = blockIdx.x * 32, k0 = blockIdx.y * 32;
    int tx = threadIdx.x, ty = threadIdx.y;  // (32,8)
#pragma unroll
    for (int i = 0; i < 4; i++)
        tile[ty + 8 * i][tx] = in[(size_t)(k0 + ty + 8 * i) * N + (n0 + tx)];
    __syncthreads();
#pragma unroll
    for (int i = 0; i < 4; i++)
        out[(size_t)(outRowOff + n0 + ty + 8 * i) * outLd + (k0 + tx)] = f2b(tile[tx][ty + 8 * i]);
}

// ---------------- Wq+Wk transpose (one launch, z selects) -> hi/lo bf16 [1536][768] ----------------
__global__ void wt_split2_kernel(const float* __restrict__ Wq, const float* __restrict__ Wk,
                                 unsigned short* __restrict__ oh, unsigned short* __restrict__ ol) {
    const float* in = blockIdx.z ? Wk : Wq;
    int outRowOff = blockIdx.z * EMBED;
    __shared__ float tile[32][33];
    int n0 = blockIdx.x * 32, k0 = blockIdx.y * 32;
    int tx = threadIdx.x, ty = threadIdx.y;  // (32,8)
#pragma unroll
    for (int i = 0; i < 4; i++)
        tile[ty + 8 * i][tx] = in[(size_t)(k0 + ty + 8 * i) * EMBED + (n0 + tx)];
    __syncthreads();
#pragma unroll
    for (int i = 0; i < 4; i++) {
        float v = tile[tx][ty + 8 * i];
        unsigned short h = f2b(v);
        size_t idx = (size_t)(outRowOff + n0 + ty + 8 * i) * EMBED + (k0 + tx);
        oh[idx] = h;
        ol[idx] = f2b(v - b2f(h));
    }
}

// ---------------- per-batch V transpose: vbuf[row][768] -> VT[768][KPAD], zero k>=577 ----------------
__global__ void vt_kernel(const unsigned short* __restrict__ vbuf, unsigned short* __restrict__ vt) {
    int z = blockIdx.z;
    int d0 = blockIdx.x * 32, c0 = blockIdx.y * 32;
    __shared__ unsigned short tile[32][33];
    int tx = threadIdx.x, ty = threadIdx.y;  // (32,8)
#pragma unroll
    for (int i = 0; i < 4; i++) {
        int c = c0 + ty + 8 * i;
        tile[ty + 8 * i][tx] = (c < SEQ) ? vbuf[((size_t)z * SEQ + c) * EMBED + d0 + tx]
                                         : (unsigned short)0;
    }
    __syncthreads();
#pragma unroll
    for (int i = 0; i < 4; i++) {
        int d = d0 + 8 * i + ty, c = c0 + tx;
        vt[(size_t)z * EMBED * KPAD + (size_t)d * KPAD + c] = tile[tx][ty + 8 * i];
    }
}

// ---------------- GEMM: C = A[M,K] * B^T  (B stored [N,K] row-major, bf16) ----------------
// hp-geometry: 256x128 tile, 512 thr (8 waves, 4Mx2N, per-wave 64x64), BK=96:
// THREE 32-k slices per barrier window -> 48 MFMA/wave/window (hp-kernel efficiency).
// LDS 72KB (As 3x16KB + Bs 3x8KB) -> 2 blocks/CU = 16 waves. Ragged K via per-slice guards.
// EPI 0: bf16; EPI 2: fp32 E[oidx]+acc; EPI 3: bf16 gelu(acc+E[col]); EPI 4: C += acc+E[col]
template <int EPI>
__global__ __launch_bounds__(512, 4) void gemm_bt(
    const unsigned short* __restrict__ A, int lda, long long sA,
    const unsigned short* __restrict__ B, int ldb, long long sB,
    int M, int N, int K,
    void* __restrict__ C, int ldc, long long sC,
    const float* __restrict__ E, long long sE) {
    __shared__ unsigned short As[3][8192];   // [slice][256 rows x 32 k]
    __shared__ unsigned short Bs[3][4096];   // [slice][128 rows x 32 k]
    int z = blockIdx.z;
    A += (size_t)z * sA;
    B += (size_t)z * sB;
    int nx = gridDim.x;
    int lin = swz_lin();
    int row0 = (lin / nx) * 256, col0 = (lin % nx) * 128;
    int t = threadIdx.x, l = t & 63, w = t >> 6;
    int wr = w >> 1, wc = w & 1;            // 4M x 2N waves
    int l15 = l & 15, kb = l >> 4;

    f32x4 acc[4][4] = {};

    int srow = t >> 2;                       // 0..127
    int kboff = ((t & 3) ^ ((srow >> 1) & 3)) * 8;

    // hoisted global element-offsets (32-bit; all tensors < 2^31 elements)
    int aoE[2], boE;
#pragma unroll
    for (int c = 0; c < 2; ++c) {
        int ar = row0 + c * 128 + srow; ar = ar < M ? ar : M - 1;
        aoE[c] = ar * lda + kboff;
    }
    {
        int br = col0 + srow; br = br < N ? br : N - 1;
        boE = br * ldb + kboff;
    }
    // hoisted LDS fragment element-offsets (XOR invariant: (r+128)>>1 ≡ r>>1 mod 4)
    int aoff[4], boff[4];
#pragma unroll
    for (int m = 0; m < 4; m++) {
        int r = wr * 64 + m * 16 + l15;      // 0..255
        aoff[m] = r * 32 + (kb ^ ((r >> 1) & 3)) * 8;
        int rn = wc * 64 + m * 16 + l15;     // 0..127
        boff[m] = rn * 32 + (kb ^ ((rn >> 1) & 3)) * 8;
    }

    auto compute = [&](int sl) {
        bf16x8 af[4], bfr[4];
#pragma unroll
        for (int m = 0; m < 4; m++) af[m] = *reinterpret_cast<const bf16x8*>(&As[sl][aoff[m]]);
#pragma unroll
        for (int n = 0; n < 4; n++) bfr[n] = *reinterpret_cast<const bf16x8*>(&Bs[sl][boff[n]]);
#pragma unroll
        for (int m = 0; m < 4; m++)
#pragma unroll
            for (int n = 0; n < 4; n++)
                acc[m][n] = __builtin_amdgcn_mfma_f32_16x16x32_bf16(af[m], bfr[n], acc[m][n], 0, 0, 0);
    };

    int ldsoff = t * 8;
    for (int kt = 0; kt < K; kt += 96) {
#pragma unroll
        for (int s = 0; s < 3; ++s) {
            int ks = kt + 32 * s;
            if (ks < K) {
                gld16(A + (size_t)(aoE[0] + ks), &As[s][ldsoff]);
                gld16(A + (size_t)(aoE[1] + ks), &As[s][4096 + ldsoff]);
                gld16(B + (size_t)(boE + ks), &Bs[s][ldsoff]);
            }
        }
        asm volatile("s_waitcnt vmcnt(0)" ::: "memory");
        __builtin_amdgcn_s_barrier();
        __builtin_amdgcn_sched_barrier(0);
#pragma unroll
        for (int s = 0; s < 3; ++s)
            if (kt + 32 * s < K) compute(s);
        __builtin_amdgcn_s_barrier();   // reads consumed (MFMA data-dep) -> safe to restage
        __builtin_amdgcn_sched_barrier(0);
    }

    // epilogue: C/D layout col = lane&15, row = (lane>>4)*4 + reg  [m89/m91 verified]
    int rbase = row0 + wr * 64 + (l >> 4) * 4;
    int cbase = col0 + wc * 64 + l15;
    auto epi = [&](bool chk) {
#pragma unroll
        for (int m = 0; m < 4; m++) {
#pragma unroll
            for (int n = 0; n < 4; n++) {
                int col = cbase + n * 16;
                if (chk && col >= N) continue;
#pragma unroll
                for (int j = 0; j < 4; j++) {
                    int row = rbase + m * 16 + j;
                    if (chk && row >= M) continue;
                    float v = acc[m][n][j];
                    size_t oidx = (size_t)z * sC + (size_t)row * ldc + col;
                    if (EPI == 0) {
                        ((unsigned short*)C)[oidx] = f2b(v);
                    } else if (EPI == 2) {
                        ((float*)C)[oidx] = E[oidx] + v;
                    } else if (EPI == 3) {
                        ((unsigned short*)C)[oidx] = f2b(gelu_f(v + E[col]));
                    } else if (EPI == 4) {
                        ((float*)C)[oidx] += v + E[col];
                    }
                }
            }
        }
    };
    if (row0 + 256 <= M && col0 + 128 <= N) epi(false); else epi(true);
}

// ---------------- High-precision GEMM (R10-exact): 256x128, 512 thr, BK=32, LDS 48KB ----------------
// (Ah+Al)*(Bh+Bl)^T via 3 MFMA passes.
// EPI 0: split-store bf16 hi/lo planes (C, C+planeOff)     (Q,K projection)
// EPI 1: store fp32  2*acc - E[z*sE+col]                   (S scores; E=ksq)
template <int EPI>
__global__ __launch_bounds__(512, 2) void gemm_hp(
    const unsigned short* __restrict__ Ah, const unsigned short* __restrict__ Al, int lda, long long sA,
    const unsigned short* __restrict__ Bh, const unsigned short* __restrict__ Bl, int ldb, long long sB,
    int M, int N, int K,
    void* __restrict__ C, int ldc, long long sC, long long planeOff,
    const float* __restrict__ E, long long sE) {
    __shared__ unsigned short Ash[8192], Asl[8192], Bsh[4096], Bsl[4096];
    int z = blockIdx.z;
    Ah += (size_t)z * sA; Al += (size_t)z * sA;
    Bh += (size_t)z * sB; Bl += (size_t)z * sB;
    int nx = gridDim.x;
    int lin = swz_lin();
    int row0 = (lin / nx) * 256, col0 = (lin % nx) * 128;
    int t = threadIdx.x, l = t & 63, w = t >> 6;
    int wr = w >> 1, wc = w & 1;
    int l15 = l & 15, kb = l >> 4;

    f32x4 acc[4][4] = {};

    int srow = t >> 2;
    int kboff = ((t & 3) ^ ((srow >> 1) & 3)) * 8;

    int aoE[2], boE;
#pragma unroll
    for (int c = 0; c < 2; ++c) {
        int ar = row0 + c * 128 + srow; ar = ar < M ? ar : M - 1;
        aoE[c] = ar * lda + kboff;
    }
    {
        int br = col0 + srow; br = br < N ? br : N - 1;
        boE = br * ldb + kboff;
    }
    int aoff[4], boff[4];
#pragma unroll
    for (int m = 0; m < 4; m++) {
        int r = wr * 64 + m * 16 + l15;
        aoff[m] = r * 32 + (kb ^ ((r >> 1) & 3)) * 8;
        int rn = wc * 64 + m * 16 + l15;
        boff[m] = rn * 32 + (kb ^ ((rn >> 1) & 3)) * 8;
    }

    int ldsoff = t * 8;
    for (int kt = 0; kt < K; kt += 32) {
        gld16(Ah + (size_t)(aoE[0] + kt), &Ash[ldsoff]);
        gld16(Ah + (size_t)(aoE[1] + kt), &Ash[4096 + ldsoff]);
        gld16(Al + (size_t)(aoE[0] + kt), &Asl[ldsoff]);
        gld16(Al + (size_t)(aoE[1] + kt), &Asl[4096 + ldsoff]);
        gld16(Bh + (size_t)(boE + kt), &Bsh[ldsoff]);
        gld16(Bl + (size_t)(boE + kt), &Bsl[ldsoff]);
        __syncthreads();
        bf16x8 afh[4], afl[4], bfh[4], bfl[4];
#pragma unroll
        for (int m = 0; m < 4; m++) {
            afh[m] = *reinterpret_cast<const bf16x8*>(&Ash[aoff[m]]);
            afl[m] = *reinterpret_cast<const bf16x8*>(&Asl[aoff[m]]);
        }
#pragma unroll
        for (int n = 0; n < 4; n++) {
            bfh[n] = *reinterpret_cast<const bf16x8*>(&Bsh[boff[n]]);
            bfl[n] = *reinterpret_cast<const bf16x8*>(&Bsl[boff[n]]);
        }
#pragma unroll
        for (int m = 0; m < 4; m++)
#pragma unroll
            for (int n = 0; n < 4; n++) {
                acc[m][n] = __builtin_amdgcn_mfma_f32_16x16x32_bf16(afh[m], bfh[n], acc[m][n], 0, 0, 0);
                acc[m][n] = __builtin_amdgcn_mfma_f32_16x16x32_bf16(afh[m], bfl[n], acc[m][n], 0, 0, 0);
                acc[m][n] = __builtin_amdgcn_mfma_f32_16x16x32_bf16(afl[m], bfh[n], acc[m][n], 0, 0, 0);
            }
        __syncthreads();
    }

    int rbase = row0 + wr * 64 + (l >> 4) * 4;
    int cbase = col0 + wc * 64 + l15;
    auto epi = [&](bool chk) {
#pragma unroll
        for (int m = 0; m < 4; m++) {
#pragma unroll
            for (int n = 0; n < 4; n++) {
                int col = cbase + n * 16;
                if (chk && col >= N) continue;
#pragma unroll
                for (int j = 0; j < 4; j++) {
                    int row = rbase + m * 16 + j;
                    if (chk && row >= M) continue;
                    float v = acc[m][n][j];
                    size_t oidx = (size_t)z * sC + (size_t)row * ldc + col;
                    if (EPI == 0) {
                        unsigned short h = f2b(v);
                        ((unsigned short*)C)[oidx] = h;
                        ((unsigned short*)C)[oidx + planeOff] = f2b(v - b2f(h));
                    } else if (EPI == 1) {
                        ((float*)C)[oidx] = 2.0f * v - E[(size_t)z * sE + col];
                    }
                }
            }
        }
    };
    if (row0 + 256 <= M && col0 + 128 <= N) epi(false); else epi(true);
}

extern "C" void kernel_launch(void* const* d_in, const int* in_sizes, int n_in,
                              void* d_out, int out_size, void* d_ws, size_t ws_size,
                              hipStream_t stream) {
    const float* x   = (const float*)d_in[0];
    const float* Wq  = (const float*)d_in[1];
    const float* Wk  = (const float*)d_in[2];
    const float* Wv  = (const float*)d_in[3];
    const float* g1  = (const float*)d_in[4];
    const float* be1 = (const float*)d_in[5];
    const float* g2  = (const float*)d_in[6];
    const float* be2 = (const float*)d_in[7];
    const float* W1  = (const float*)d_in[8];
    const float* bb1 = (const float*)d_in[9];
    const float* W2  = (const float*)d_in[10];
    const float* bb2 = (const float*)d_in[11];
    float* out = (float*)d_out;

    char* ws = (char*)d_ws;
    size_t off = 0;
    auto alloc = [&](size_t bytes) -> char* {
        char* p = ws + off;
        off += (bytes + 255) & ~(size_t)255;
        return p;
    };
    unsigned short* wqkTh = (unsigned short*)alloc((size_t)1536 * EMBED * 2);
    unsigned short* wqkTl = (unsigned short*)alloc((size_t)1536 * EMBED * 2);
    unsigned short* wvT   = (unsigned short*)alloc((size_t)EMBED * EMBED * 2);
    unsigned short* w1T   = (unsigned short*)alloc((size_t)HIDDEN * EMBED * 2);
    unsigned short* w2T   = (unsigned short*)alloc((size_t)EMBED * HIDDEN * 2);
    float*          ksqb  = (float*)alloc((size_t)ROWS * 4);
    char* regB = alloc((size_t)ROWS * HIDDEN * 2);
    char* regC = alloc((size_t)2 * ROWS * EMBED * 2);
    unsigned short* vbuf  = (unsigned short*)alloc((size_t)ROWS * EMBED * 2);
    unsigned short* vtb   = (unsigned short*)alloc((size_t)BATCH * EMBED * KPAD * 2);
    unsigned short* Pbuf  = (unsigned short*)alloc((size_t)ROWS * KPAD * 2);
    if (off > ws_size) return;

    unsigned short* qkh  = (unsigned short*)regB;
    unsigned short* qkl  = qkh + (size_t)ROWS * 1536;
    unsigned short* hid  = (unsigned short*)regB;
    unsigned short* h1h  = (unsigned short*)regC;
    unsigned short* h1l  = h1h + (size_t)ROWS * EMBED;
    float*          Sbuf = (float*)regC;
    unsigned short* h2   = (unsigned short*)regC;

    dim3 b256(256), b512(512), bT(32, 8);

    wt_split2_kernel<<<dim3(24, 24, 2), bT, 0, stream>>>(Wq, Wk, wqkTh, wqkTl);
    wt_kernel<<<dim3(24, 24), bT, 0, stream>>>(Wv, wvT, EMBED, EMBED, 0, EMBED);
    wt_kernel<<<dim3(96, 24), bT, 0, stream>>>(W1, w1T, EMBED, HIDDEN, 0, EMBED);
    wt_kernel<<<dim3(24, 96), bT, 0, stream>>>(W2, w2T, HIDDEN, EMBED, 0, HIDDEN);

    // h1 = LN1(x) -> hi/lo planes
    ln_split_kernel<<<ROWS, b256, 0, stream>>>(x, g1, be1, h1h, h1l);

    // [Q|K] = h1 @ Wqk^T  (high precision, split-stored)  256x128 tiles
    gemm_hp<0><<<dim3(12, 73, 1), b512, 0, stream>>>(
        h1h, h1l, EMBED, 0, wqkTh, wqkTl, EMBED, 0,
        ROWS, 1536, EMBED, qkh, 1536, 0, (long long)ROWS * 1536, nullptr, 0);

    // V = h1 @ Wv^T   (256x128 / BK=96)
    gemm_bt<0><<<dim3(6, 73, 1), b512, 0, stream>>>(
        h1h, EMBED, 0, wvT, EMBED, 0, ROWS, EMBED, EMBED, vbuf, EMBED, 0, nullptr, 0);

    // ksq from hi/lo K
    ksq_kernel<<<ROWS, b256, 0, stream>>>(qkh, qkl, ksqb);

    // S = 2*Q@K^T - ksq   (batched, high precision, 256x128 tiles)
    gemm_hp<1><<<dim3(5, 3, 32), b512, 0, stream>>>(
        qkh, qkl, 1536, (long long)SEQ * 1536, qkh + EMBED, qkl + EMBED, 1536, (long long)SEQ * 1536,
        SEQ, SEQ, EMBED, Sbuf, SLD, (long long)SEQ * SLD, 0, ksqb, SEQ);

    // P = softmax(S)
    softmax_kernel<<<ROWS, b256, 0, stream>>>(Sbuf, Pbuf);

    // VT per batch
    vt_kernel<<<dim3(24, 19, 32), bT, 0, stream>>>(vbuf, vtb);

    // out = x + P @ V   (batched, 256x128 / BK=96, ragged K=608)
    gemm_bt<2><<<dim3(6, 3, 32), b512, 0, stream>>>(
        Pbuf, KPAD, (long long)SEQ * KPAD, vtb, KPAD, (long long)EMBED * KPAD,
        SEQ, EMBED, KPAD, out, EMBED, (long long)SEQ * EMBED, x, (long long)SEQ * EMBED);

    // h2 = LN2(out)
    ln_kernel<<<ROWS, b256, 0, stream>>>(out, g2, be2, h2);

    // hidden = gelu(h2 @ W1 + b1)   (256x128 / BK=96)
    gemm_bt<3><<<dim3(24, 73, 1), b512, 0, stream>>>(
        h2, EMBED, 0, w1T, EMBED, 0, ROWS, HIDDEN, EMBED, hid, HIDDEN, 0, bb1, 0);

    // out += hidden @ W2 + b2       (256x128 / BK=96)
    gemm_bt<4><<<dim3(6, 73, 1), b512, 0, stream>>>(
        hid, HIDDEN, 0, w2T, HIDDEN, 0, ROWS, EMBED, HIDDEN, out, EMBED, 0, bb2, 0);
}